// Round 13
// baseline (39.238 us; speedup 1.0000x reference)
//
#include <hip/hip_runtime.h>
#include <hip/hip_bf16.h>

typedef __attribute__((ext_vector_type(8))) short short8;
typedef __attribute__((ext_vector_type(4))) float f32x4;

#define N_TOT 8192
#define HALF_B 4096
#define D 128
#define BM 256               // rows per block (64 per wave)
#define BN 128               // cols per B-tile step
#define NQ 16                // column slices (grid.y)
#define SLICE (N_TOT / NQ)   // 512 cols per block
#define NSTEP (SLICE / BN)   // 4 steps
// z pre-scaled by SCALE, SCALE^2 = 2*log2(e): z@z^T = sim/T * log2(e)
#define SCALE 1.6986437f
#define CDIAG 7.3890561f     // e^2 == exp2(SCALE^2): diagonal term (R7-verified)

#if __has_builtin(__builtin_amdgcn_exp2f)
  #define EXP2(x) __builtin_amdgcn_exp2f(x)
#else
  #define EXP2(x) exp2f(x)
#endif

static __device__ inline unsigned short f2bf(float f) {
    unsigned int u = __builtin_bit_cast(unsigned int, f);
    u = (u + 0x7fffu + ((u >> 16) & 1u)) >> 16;
    return (unsigned short)u;
}

// async global->LDS, 16B per lane, LDS dest = wave-uniform base + lane*16
static __device__ __forceinline__ void gload16(const void* g, void* l) {
    __builtin_amdgcn_global_load_lds(
        (const __attribute__((address_space(1))) unsigned int*)g,
        (__attribute__((address_space(3))) unsigned int*)l, 16, 0, 0);
}

// Stage a 128x128 bf16 tile into 32 KB LDS, XOR-swizzled (row&15)<<4 via the
// GLOBAL source address (gload_lds writes LDS linearly - rule #21).
static __device__ __forceinline__ void stage_tile(const unsigned short* __restrict__ z,
                                                  int src_row, char* ldsbase, int tid) {
    int wv = tid >> 6, ln = tid & 63;
    const char* zb = (const char*)z;
    #pragma unroll
    for (int i = 0; i < 8; ++i) {
        int L  = wv * 8192 + i * 1024;        // wave-uniform LDS byte offset
        int Ll = L + ln * 16;                 // this lane's linear dest byte
        int r  = Ll >> 8;
        int c2 = (Ll & 255) ^ ((r & 15) << 4);
        gload16(zb + (size_t)(src_row + r) * 256 + c2, ldsbase + L);
    }
}

// swizzled LDS fragment read (16B), same involution as stage_tile
static __device__ __forceinline__ short8 ldsfrag(const char* ldsbase, int row, int kbyte) {
    int off = row * 256 + (kbyte ^ ((row & 15) << 4));
    return *reinterpret_cast<const short8*>(ldsbase + off);
}

// ---- Kernel 1: normalize row PAIRS, emit z + fp32 pos logits -------------
// grid 1024 x 256: wave w handles pair r = blk*4+w (rows r and r+4096)
__global__ __launch_bounds__(256) void nrm_k(const float* __restrict__ pi,
                                             const float* __restrict__ pj,
                                             unsigned short* __restrict__ z,
                                             float* __restrict__ ppos) {
    int tid = (int)threadIdx.x;
    int wid = tid >> 6, lane = tid & 63;
    int r = (int)blockIdx.x * 4 + wid;                         // pair index [0,4096)
    float2 va = *reinterpret_cast<const float2*>(pi + (size_t)r * D + lane * 2);
    float2 vb = *reinterpret_cast<const float2*>(pj + (size_t)r * D + lane * 2);
    float ssa = va.x * va.x + va.y * va.y;
    float ssb = vb.x * vb.x + vb.y * vb.y;
    float sab = va.x * vb.x + va.y * vb.y;
    #pragma unroll
    for (int off = 32; off >= 1; off >>= 1) {
        ssa += __shfl_xor(ssa, off);
        ssb += __shfl_xor(ssb, off);
        sab += __shfl_xor(sab, off);
    }
    float na = fmaxf(sqrtf(ssa), 1e-8f);
    float nb = fmaxf(sqrtf(ssb), 1e-8f);
    float inva = SCALE / na, invb = SCALE / nb;
    unsigned int pa = ((unsigned int)f2bf(va.y * inva) << 16) | (unsigned int)f2bf(va.x * inva);
    unsigned int pb = ((unsigned int)f2bf(vb.y * invb) << 16) | (unsigned int)f2bf(vb.x * invb);
    *reinterpret_cast<unsigned int*>(z + (size_t)r * D + lane * 2) = pa;
    *reinterpret_cast<unsigned int*>(z + (size_t)(r + HALF_B) * D + lane * 2) = pb;
    if (lane == 0) ppos[r] = 2.0f * sab / (na * nb);   // pos_sim / T, fp32
}

// ---- Kernel 2: z@z^T, 64 rows/wave (halved LDS B-read amplification) -----
// grid (32, 16), block 256. A (256x128) staged through Asm in two halves,
// frags held in 64 VGPRs/thread; B single-buffered in Bsm (R10 loop shape).
__global__ __launch_bounds__(256, 2) void sim_k(const unsigned short* __restrict__ z,
                                                float* __restrict__ s_part) {
    __shared__ char lds[64 * 1024];
    char* Asm = lds;
    char* Bsm = lds + 32768;

    int tid  = (int)threadIdx.x;
    int lane = tid & 63;
    int wid  = tid >> 6;
    int lr   = lane & 15;     // A-row / B-col within 16-tile
    int kg   = lane >> 4;     // k-group
    int R0   = (int)blockIdx.x * BM;
    int C0   = (int)blockIdx.y * SLICE;

    stage_tile(z, R0, Asm, tid);          // A rows 0-127
    stage_tile(z, C0, Bsm, tid);          // B step 0
    __syncthreads();

    // A fragments: 64 rows x K=128 per wave (64 VGPRs), read from LDS halves
    short8 a[4][4];
    if (wid < 2) {
        #pragma unroll
        for (int m = 0; m < 4; ++m)
            #pragma unroll
            for (int kt = 0; kt < 4; ++kt)
                a[m][kt] = ldsfrag(Asm, (wid & 1) * 64 + m * 16 + lr, kg * 16 + kt * 64);
    }
    __syncthreads();                      // waves 0-1 done with Asm half 0
    stage_tile(z, R0 + 128, Asm, tid);    // A rows 128-255
    __syncthreads();
    if (wid >= 2) {
        #pragma unroll
        for (int m = 0; m < 4; ++m)
            #pragma unroll
            for (int kt = 0; kt < 4; ++kt)
                a[m][kt] = ldsfrag(Asm, (wid & 1) * 64 + m * 16 + lr, kg * 16 + kt * 64);
    }
    // waves 0-1 may run ahead into compute (reads Bsm only); they rejoin at
    // the first step barrier. Asm is not written again.

    float s[4][4];
    #pragma unroll
    for (int m = 0; m < 4; ++m)
        #pragma unroll
        for (int r = 0; r < 4; ++r) s[m][r] = 0.0f;

    for (int bs = 0; bs < NSTEP; ++bs) {
        if (bs) {
            __syncthreads();                       // readers done with Bsm
            stage_tile(z, C0 + bs * BN, Bsm, tid);
            __syncthreads();                       // stage visible
        }
        #pragma unroll
        for (int nt = 0; nt < 8; ++nt) {
            short8 b[4];
            #pragma unroll
            for (int kt = 0; kt < 4; ++kt)
                b[kt] = ldsfrag(Bsm, nt * 16 + lr, kg * 16 + kt * 64);
            #pragma unroll
            for (int m = 0; m < 4; ++m) {
                f32x4 acc = {0.0f, 0.0f, 0.0f, 0.0f};
                #pragma unroll
                for (int kt = 0; kt < 4; ++kt)
                    acc = __builtin_amdgcn_mfma_f32_16x16x32_bf16(a[m][kt], b[kt], acc, 0, 0, 0);
                #pragma unroll
                for (int r = 0; r < 4; ++r)
                    s[m][r] += EXP2(acc[r]);   // includes diag (== CDIAG, fixed in red_k)
            }
        }
    }

    // reduce across the 16 columns held by each 16-lane group
    #pragma unroll
    for (int off = 1; off <= 8; off <<= 1)
        #pragma unroll
        for (int m = 0; m < 4; ++m)
            #pragma unroll
            for (int r = 0; r < 4; ++r)
                s[m][r] += __shfl_xor(s[m][r], off);

    if (lr == 0) {
        int rowbase = R0 + wid * 64;
        #pragma unroll
        for (int m = 0; m < 4; ++m)
            #pragma unroll
            for (int r = 0; r < 4; ++r)
                s_part[(size_t)(rowbase + m * 16 + kg * 4 + r) * NQ + blockIdx.y] = s[m][r];
    }
}

// ---- Kernel 3: single-block finish: S -> log -> deterministic sum --------
// 1024 threads x 8 rows each; s_part[row][16] read as 4x float4 (coalesced).
__global__ __launch_bounds__(1024) void red_k(const float* __restrict__ s_part,
                                              const float* __restrict__ ppos,
                                              float* __restrict__ out) {
    int tid = (int)threadIdx.x;
    float acc = 0.0f;
    #pragma unroll
    for (int u = 0; u < 8; ++u) {
        int row = tid + u * 1024;
        const f32x4* p = reinterpret_cast<const f32x4*>(s_part + (size_t)row * NQ);
        float S = 0.0f;
        #pragma unroll
        for (int q = 0; q < 4; ++q) {
            f32x4 v = p[q];
            S += (v[0] + v[1]) + (v[2] + v[3]);
        }
        acc += __logf(S - CDIAG) - ppos[row & (HALF_B - 1)];
    }
    #pragma unroll
    for (int off = 32; off >= 1; off >>= 1) acc += __shfl_xor(acc, off);
    __shared__ float ls[16];
    if ((tid & 63) == 0) ls[tid >> 6] = acc;
    __syncthreads();
    if (tid < 16) {
        float w = ls[tid];
        #pragma unroll
        for (int off = 8; off >= 1; off >>= 1) w += __shfl_xor(w, off);
        if (tid == 0) out[0] = w * (1.0f / (float)N_TOT);
    }
}

extern "C" void kernel_launch(void* const* d_in, const int* in_sizes, int n_in,
                              void* d_out, int out_size, void* d_ws, size_t ws_size,
                              hipStream_t stream) {
    const float* pi = (const float*)d_in[0];
    const float* pj = (const float*)d_in[1];
    float* out = (float*)d_out;

    char* ws = (char*)d_ws;
    unsigned short* z = (unsigned short*)ws;                         // 2 MiB
    float* ppos   = (float*)(ws + 2 * 1024 * 1024);                  // 16 KiB
    float* s_part = (float*)(ws + 2 * 1024 * 1024 + 16 * 1024);      // 512 KiB ([row][NQ])

    nrm_k<<<dim3(1024), dim3(256), 0, stream>>>(pi, pj, z, ppos);
    sim_k<<<dim3(N_TOT / BM, NQ), dim3(256), 0, stream>>>(z, s_part);
    red_k<<<dim3(1), dim3(1024), 0, stream>>>(s_part, ppos, out);
}

// Round 14
// 34.642 us; speedup vs baseline: 1.1327x; 1.1327x over previous
//
#include <hip/hip_runtime.h>
#include <hip/hip_bf16.h>

typedef __attribute__((ext_vector_type(4))) float f32x4;

#define N_TOT 8192
#define HALF_B 4096
#define D 128
#define BM 128               // rows per block
#define BN 128               // cols per B-tile step
#define NQ 16                // column slices (grid.y)
#define SLICE (N_TOT / NQ)   // 512 cols per block
#define NSTEP (SLICE / BN)   // 4 steps
// z pre-scaled by SCALE, SCALE^2 = 2*log2(e): z@z^T = sim/T * log2(e)
#define SCALE 1.6986437f
#define CDIAG 7.3890561f     // e^2 == exp2(SCALE^2): diagonal term (R7-verified)

#if __has_builtin(__builtin_amdgcn_exp2f)
  #define EXP2(x) __builtin_amdgcn_exp2f(x)
#else
  #define EXP2(x) exp2f(x)
#endif

// ---- fp8 e4m3fn RNE converter (self-contained) ---------------------------
static __device__ __forceinline__ unsigned char f2e4m3(float x) {
    unsigned int u = __builtin_bit_cast(unsigned int, x);
    unsigned char s = (unsigned char)((u >> 24) & 0x80u);
    unsigned int a = u & 0x7fffffffu;
    float ax = __builtin_bit_cast(float, a);
    if (ax >= 464.0f) return (unsigned char)(s | 0x7Eu);     // saturate 448
    int e = (int)(a >> 23) - 127;
    if (e < -6) {                                            // subnormal (granule 2^-9)
        int n = (int)lrintf(ax * 512.0f);                    // RNE; n==8 -> min normal code
        return (unsigned char)(s | (unsigned char)n);
    }
    unsigned int m = a & 0x7fffffu;
    unsigned int mr = m + 0x7FFFFu + ((m >> 20) & 1u);       // RNE at 3 mantissa bits
    if (mr >= 0x800000u) { mr = 0; ++e; }
    if (e > 8) return (unsigned char)(s | 0x7Eu);
    return (unsigned char)(s | (unsigned int)((e + 7) << 3) | (mr >> 20));
}

// async global->LDS, 16B per lane, LDS dest = wave-uniform base + lane*16
static __device__ __forceinline__ void gload16(const void* g, void* l) {
    __builtin_amdgcn_global_load_lds(
        (const __attribute__((address_space(1))) unsigned int*)g,
        (__attribute__((address_space(3))) unsigned int*)l, 16, 0, 0);
}

// Stage a 128x128 fp8 tile (16 KB) into LDS, XOR-swizzled (r&7)<<4 on 16B
// granules via the GLOBAL source address (gload_lds writes LDS linearly).
static __device__ __forceinline__ void stage_tile8(const unsigned char* __restrict__ z8,
                                                   int src_row, char* ldsbase, int tid) {
    int wv = tid >> 6, ln = tid & 63;
    #pragma unroll
    for (int i = 0; i < 4; ++i) {
        int L  = wv * 4096 + i * 1024;        // wave-uniform LDS byte offset
        int Ll = L + ln * 16;                 // this lane's linear dest byte
        int r  = Ll >> 7;                     // 128 B per row
        int c2 = (Ll & 127) ^ ((r & 7) << 4);
        gload16(z8 + (size_t)(src_row + r) * 128 + c2, ldsbase + L);
    }
}

// swizzled LDS fragment read (8B = one fp8 MFMA operand), same involution
static __device__ __forceinline__ long ldsfrag8(const char* ldsbase, int row, int kbyte) {
    int off = row * 128 + (kbyte ^ ((row & 7) << 4));
    return *reinterpret_cast<const long*>(ldsbase + off);
}

// ---- Kernel 1: normalize row PAIRS, emit fp8 z8 + fp32 pos logits --------
// grid 1024 x 256: wave w handles pair r = blk*4+w (rows r and r+4096)
__global__ __launch_bounds__(256) void nrm_k(const float* __restrict__ pi,
                                             const float* __restrict__ pj,
                                             unsigned char* __restrict__ z8,
                                             float* __restrict__ ppos) {
    int tid = (int)threadIdx.x;
    int wid = tid >> 6, lane = tid & 63;
    int r = (int)blockIdx.x * 4 + wid;                         // pair index [0,4096)
    float2 va = *reinterpret_cast<const float2*>(pi + (size_t)r * D + lane * 2);
    float2 vb = *reinterpret_cast<const float2*>(pj + (size_t)r * D + lane * 2);
    float ssa = va.x * va.x + va.y * va.y;
    float ssb = vb.x * vb.x + vb.y * vb.y;
    float sab = va.x * vb.x + va.y * vb.y;
    #pragma unroll
    for (int off = 32; off >= 1; off >>= 1) {
        ssa += __shfl_xor(ssa, off);
        ssb += __shfl_xor(ssb, off);
        sab += __shfl_xor(sab, off);
    }
    float na = fmaxf(sqrtf(ssa), 1e-8f);
    float nb = fmaxf(sqrtf(ssb), 1e-8f);
    float inva = SCALE / na, invb = SCALE / nb;
    unsigned short qa = (unsigned short)f2e4m3(va.x * inva)
                      | ((unsigned short)f2e4m3(va.y * inva) << 8);
    unsigned short qb = (unsigned short)f2e4m3(vb.x * invb)
                      | ((unsigned short)f2e4m3(vb.y * invb) << 8);
    *reinterpret_cast<unsigned short*>(z8 + (size_t)r * D + lane * 2) = qa;
    *reinterpret_cast<unsigned short*>(z8 + (size_t)(r + HALF_B) * D + lane * 2) = qb;
    if (lane == 0) ppos[r] = 2.0f * sab / (na * nb);   // pos_sim / T, fp32 exact
}

// ---- Kernel 2: fp8 LDS-staged z@z^T -> exp2 -> row partial sums ----------
// grid (64, 16), block 256 (4 waves x 32 rows). LDS = 32 KB -> 4 blocks/CU.
__global__ __launch_bounds__(256, 4) void sim_k(const unsigned char* __restrict__ z8,
                                                float* __restrict__ s_part) {
    __shared__ char lds[32 * 1024];
    char* Asm = lds;               // 16 KB, live whole kernel
    char* Bsm = lds + 16384;       // 16 KB, restaged per step

    int tid  = (int)threadIdx.x;
    int lane = tid & 63;
    int wid  = tid >> 6;
    int lr   = lane & 15;     // A-row / B-col within 16-tile
    int kg   = lane >> 4;     // k-group (8 consecutive k bytes)
    int R0   = (int)blockIdx.x * BM;
    int C0   = (int)blockIdx.y * SLICE;

    stage_tile8(z8, R0, Asm, tid);
    stage_tile8(z8, C0, Bsm, tid);
    __syncthreads();

    // A fragments: wave's 32 rows x K=128, read once from LDS (16 VGPRs)
    long a[2][4];
    #pragma unroll
    for (int m = 0; m < 2; ++m)
        #pragma unroll
        for (int kt = 0; kt < 4; ++kt)
            a[m][kt] = ldsfrag8(Asm, wid * 32 + m * 16 + lr, kg * 8 + kt * 32);

    float s[2][4];
    #pragma unroll
    for (int m = 0; m < 2; ++m)
        #pragma unroll
        for (int r = 0; r < 4; ++r) s[m][r] = 0.0f;

    for (int bs = 0; bs < NSTEP; ++bs) {
        if (bs) {
            __syncthreads();                       // readers done with Bsm
            stage_tile8(z8, C0 + bs * BN, Bsm, tid);
            __syncthreads();                       // stage visible
        }
        #pragma unroll
        for (int nt = 0; nt < 8; ++nt) {
            long b[4];
            #pragma unroll
            for (int kt = 0; kt < 4; ++kt)
                b[kt] = ldsfrag8(Bsm, nt * 16 + lr, kg * 8 + kt * 32);
            #pragma unroll
            for (int m = 0; m < 2; ++m) {
                f32x4 acc = {0.0f, 0.0f, 0.0f, 0.0f};
                #pragma unroll
                for (int kt = 0; kt < 4; ++kt)
                    acc = __builtin_amdgcn_mfma_f32_16x16x32_fp8_fp8(a[m][kt], b[kt], acc, 0, 0, 0);
                #pragma unroll
                for (int r = 0; r < 4; ++r)
                    s[m][r] += EXP2(acc[r]);   // includes diag (== CDIAG, fixed in red_k)
            }
        }
    }

    // reduce across the 16 columns held by each 16-lane group
    #pragma unroll
    for (int off = 1; off <= 8; off <<= 1)
        #pragma unroll
        for (int m = 0; m < 2; ++m)
            #pragma unroll
            for (int r = 0; r < 4; ++r)
                s[m][r] += __shfl_xor(s[m][r], off);

    if (lr == 0) {
        int rowbase = R0 + wid * 32;
        #pragma unroll
        for (int m = 0; m < 2; ++m)
            #pragma unroll
            for (int r = 0; r < 4; ++r)
                s_part[(size_t)(rowbase + m * 16 + kg * 4 + r) * NQ + blockIdx.y] = s[m][r];
    }
}

// ---- Kernel 3: single-block finish: S -> log -> deterministic sum --------
// 1024 threads x 8 rows each; s_part[row][16] read as 4x float4 (coalesced).
__global__ __launch_bounds__(1024) void red_k(const float* __restrict__ s_part,
                                              const float* __restrict__ ppos,
                                              float* __restrict__ out) {
    int tid = (int)threadIdx.x;
    float acc = 0.0f;
    #pragma unroll
    for (int u = 0; u < 8; ++u) {
        int row = tid + u * 1024;
        const f32x4* p = reinterpret_cast<const f32x4*>(s_part + (size_t)row * NQ);
        float S = 0.0f;
        #pragma unroll
        for (int q = 0; q < 4; ++q) {
            f32x4 v = p[q];
            S += (v[0] + v[1]) + (v[2] + v[3]);
        }
        acc += __logf(S - CDIAG) - ppos[row & (HALF_B - 1)];
    }
    #pragma unroll
    for (int off = 32; off >= 1; off >>= 1) acc += __shfl_xor(acc, off);
    __shared__ float ls[16];
    if ((tid & 63) == 0) ls[tid >> 6] = acc;
    __syncthreads();
    if (tid < 16) {
        float w = ls[tid];
        #pragma unroll
        for (int off = 8; off >= 1; off >>= 1) w += __shfl_xor(w, off);
        if (tid == 0) out[0] = w * (1.0f / (float)N_TOT);
    }
}

extern "C" void kernel_launch(void* const* d_in, const int* in_sizes, int n_in,
                              void* d_out, int out_size, void* d_ws, size_t ws_size,
                              hipStream_t stream) {
    const float* pi = (const float*)d_in[0];
    const float* pj = (const float*)d_in[1];
    float* out = (float*)d_out;

    char* ws = (char*)d_ws;
    unsigned char* z8 = (unsigned char*)ws;                          // 1 MiB
    float* ppos   = (float*)(ws + 1024 * 1024);                      // 16 KiB
    float* s_part = (float*)(ws + 1024 * 1024 + 16 * 1024);          // 512 KiB ([row][NQ])

    nrm_k<<<dim3(1024), dim3(256), 0, stream>>>(pi, pj, z8, ppos);
    sim_k<<<dim3(N_TOT / BM, NQ), dim3(256), 0, stream>>>(z8, s_part);
    red_k<<<dim3(1), dim3(1024), 0, stream>>>(s_part, ppos, out);
}

// Round 15
// 32.646 us; speedup vs baseline: 1.2019x; 1.0611x over previous
//
#include <hip/hip_runtime.h>
#include <hip/hip_bf16.h>

typedef __attribute__((ext_vector_type(8))) short short8;
typedef __attribute__((ext_vector_type(4))) float f32x4;

#define N_TOT 8192
#define HALF_B 4096
#define D 128
#define BM 128               // rows per block
#define BN 128               // cols per B-tile step
#define NQ 8                 // column slices (grid.y)
#define SLICE (N_TOT / NQ)   // 1024 cols per block
#define NSTEP (SLICE / BN)   // 8 steps
// z pre-scaled by SCALE, SCALE^2 = 2*log2(e): z@z^T = sim/T * log2(e)
#define SCALE 1.6986437f
#define CDIAG 7.3890561f     // e^2 == exp2(SCALE^2): diagonal term (R7-verified)

#if __has_builtin(__builtin_amdgcn_exp2f)
  #define EXP2(x) __builtin_amdgcn_exp2f(x)
#else
  #define EXP2(x) exp2f(x)
#endif

#define SBAR()   __builtin_amdgcn_s_barrier()
#define SCHEDB() __builtin_amdgcn_sched_barrier(0)

static __device__ inline unsigned short f2bf(float f) {
    unsigned int u = __builtin_bit_cast(unsigned int, f);
    u = (u + 0x7fffu + ((u >> 16) & 1u)) >> 16;
    return (unsigned short)u;
}

// async global->LDS, 16B per lane, LDS dest = wave-uniform base + lane*16
static __device__ __forceinline__ void gload16(const void* g, void* l) {
    __builtin_amdgcn_global_load_lds(
        (const __attribute__((address_space(1))) unsigned int*)g,
        (__attribute__((address_space(3))) unsigned int*)l, 16, 0, 0);
}

// Stage a 128x128 bf16 tile into 32 KB LDS, XOR-swizzled (row&15)<<4 via the
// GLOBAL source address (gload_lds writes LDS linearly - rule #21).
// Exactly 8 gload16 per wave -> vmcnt bookkeeping unit = 8 per tile.
static __device__ __forceinline__ void stage_tile(const unsigned short* __restrict__ z,
                                                  int src_row, char* ldsbase, int tid) {
    int wv = tid >> 6, ln = tid & 63;
    const char* zb = (const char*)z;
    #pragma unroll
    for (int i = 0; i < 8; ++i) {
        int L  = wv * 8192 + i * 1024;        // wave-uniform LDS byte offset
        int Ll = L + ln * 16;                 // this lane's linear dest byte
        int r  = Ll >> 8;
        int c2 = (Ll & 255) ^ ((r & 15) << 4);
        gload16(zb + (size_t)(src_row + r) * 256 + c2, ldsbase + L);
    }
}

// swizzled LDS fragment read (16B), same involution as stage_tile
static __device__ __forceinline__ short8 ldsfrag(const char* ldsbase, int row, int kbyte) {
    int off = row * 256 + (kbyte ^ ((row & 15) << 4));
    return *reinterpret_cast<const short8*>(ldsbase + off);
}

// ---- Kernel 1: normalize row PAIRS, emit z + fp32 pos logits -------------
__global__ __launch_bounds__(256) void nrm_k(const float* __restrict__ pi,
                                             const float* __restrict__ pj,
                                             unsigned short* __restrict__ z,
                                             float* __restrict__ ppos) {
    int tid = (int)threadIdx.x;
    int wid = tid >> 6, lane = tid & 63;
    int r = (int)blockIdx.x * 4 + wid;                         // pair index [0,4096)
    float2 va = *reinterpret_cast<const float2*>(pi + (size_t)r * D + lane * 2);
    float2 vb = *reinterpret_cast<const float2*>(pj + (size_t)r * D + lane * 2);
    float ssa = va.x * va.x + va.y * va.y;
    float ssb = vb.x * vb.x + vb.y * vb.y;
    float sab = va.x * vb.x + va.y * vb.y;
    #pragma unroll
    for (int off = 32; off >= 1; off >>= 1) {
        ssa += __shfl_xor(ssa, off);
        ssb += __shfl_xor(ssb, off);
        sab += __shfl_xor(sab, off);
    }
    float na = fmaxf(sqrtf(ssa), 1e-8f);
    float nb = fmaxf(sqrtf(ssb), 1e-8f);
    float inva = SCALE / na, invb = SCALE / nb;
    unsigned int pa = ((unsigned int)f2bf(va.y * inva) << 16) | (unsigned int)f2bf(va.x * inva);
    unsigned int pb = ((unsigned int)f2bf(vb.y * invb) << 16) | (unsigned int)f2bf(vb.x * invb);
    *reinterpret_cast<unsigned int*>(z + (size_t)r * D + lane * 2) = pa;
    *reinterpret_cast<unsigned int*>(z + (size_t)(r + HALF_B) * D + lane * 2) = pb;
    if (lane == 0) ppos[r] = 2.0f * sab / (na * nb);   // pos_sim / T, fp32
}

// ---- Kernel 2: z@z^T, dbuf B with COUNTED vmcnt boundaries (T4) ----------
// grid (64, 8), block 256. B alternates Bsm <-> Asm (Asm dead after a-frag
// read). Boundary = raw s_barrier + s_waitcnt vmcnt(8): previous tile's
// loads complete, next tile's 8 stay in flight across the barrier.
__global__ __launch_bounds__(256, 2) void sim_k(const unsigned short* __restrict__ z,
                                                float* __restrict__ s_part) {
    __shared__ char lds[64 * 1024];
    char* Asm = lds;
    char* Bsm = lds + 32768;

    int tid  = (int)threadIdx.x;
    int lane = tid & 63;
    int wid  = tid >> 6;
    int lr   = lane & 15;     // A-row / B-col within 16-tile
    int kg   = lane >> 4;     // k-group
    int R0   = (int)blockIdx.x * BM;
    int C0   = (int)blockIdx.y * SLICE;

    stage_tile(z, R0, Asm, tid);
    stage_tile(z, C0, Bsm, tid);
    __syncthreads();                      // full drain once (prologue)

    // A fragments: wave's 32 rows x K=128, read once from LDS (32 VGPRs)
    short8 a[2][4];
    #pragma unroll
    for (int m = 0; m < 2; ++m)
        #pragma unroll
        for (int kt = 0; kt < 4; ++kt)
            a[m][kt] = ldsfrag(Asm, wid * 32 + m * 16 + lr, kg * 16 + kt * 64);
    __syncthreads();                      // all waves done reading Asm (lgkm drained)

    stage_tile(z, C0 + BN, Asm, tid);     // prefetch B1 into old A buffer (8 in flight)

    float s[2][4];
    #pragma unroll
    for (int m = 0; m < 2; ++m)
        #pragma unroll
        for (int r = 0; r < 4; ++r) s[m][r] = 0.0f;

    for (int bs = 0; bs < NSTEP; ++bs) {
        char* curb = (bs & 1) ? Asm : Bsm;
        #pragma unroll
        for (int nt = 0; nt < 8; ++nt) {
            short8 b[4];
            #pragma unroll
            for (int kt = 0; kt < 4; ++kt)
                b[kt] = ldsfrag(curb, nt * 16 + lr, kg * 16 + kt * 64);
            __builtin_amdgcn_s_setprio(1);
            f32x4 acc0 = {0.0f, 0.0f, 0.0f, 0.0f};
            f32x4 acc1 = {0.0f, 0.0f, 0.0f, 0.0f};
            #pragma unroll
            for (int kt = 0; kt < 4; ++kt) {
                acc0 = __builtin_amdgcn_mfma_f32_16x16x32_bf16(a[0][kt], b[kt], acc0, 0, 0, 0);
                acc1 = __builtin_amdgcn_mfma_f32_16x16x32_bf16(a[1][kt], b[kt], acc1, 0, 0, 0);
            }
            __builtin_amdgcn_s_setprio(0);
            #pragma unroll
            for (int r = 0; r < 4; ++r) {
                s[0][r] += EXP2(acc0[r]);   // includes diag (== CDIAG, fixed in red_k)
                s[1][r] += EXP2(acc1[r]);
            }
        }
        if (bs + 1 < NSTEP) {
            // all this wave's reads of curb were consumed above (MFMA->exp2
            // dependency forces lgkm completion) -> raw barrier is safe.
            SBAR(); SCHEDB();
            if (bs + 2 < NSTEP) {
                stage_tile(z, C0 + (bs + 2) * BN, curb, tid);   // 8 more in flight
                asm volatile("s_waitcnt vmcnt(8)" ::: "memory"); // bs+1 done, bs+2 flying
            } else {
                asm volatile("s_waitcnt vmcnt(0)" ::: "memory"); // warm: issued a step ago
            }
            SCHEDB();
            SBAR(); SCHEDB();             // everyone's (bs+1) stage visible
        }
    }

    // reduce across the 16 columns held by each 16-lane group
    #pragma unroll
    for (int off = 1; off <= 8; off <<= 1)
        #pragma unroll
        for (int m = 0; m < 2; ++m)
            #pragma unroll
            for (int r = 0; r < 4; ++r)
                s[m][r] += __shfl_xor(s[m][r], off);

    if (lr == 0) {
        int rowbase = R0 + wid * 32;
        #pragma unroll
        for (int m = 0; m < 2; ++m)
            #pragma unroll
            for (int r = 0; r < 4; ++r)
                s_part[(size_t)(rowbase + m * 16 + kg * 4 + r) * NQ + blockIdx.y] = s[m][r];
    }
}

// ---- Kernel 3: single-block finish: S -> log -> deterministic sum --------
__global__ __launch_bounds__(1024) void red_k(const float* __restrict__ s_part,
                                              const float* __restrict__ ppos,
                                              float* __restrict__ out) {
    int tid = (int)threadIdx.x;
    float acc = 0.0f;
    #pragma unroll
    for (int u = 0; u < 8; ++u) {
        int row = tid + u * 1024;
        f32x4 v0 = *reinterpret_cast<const f32x4*>(s_part + (size_t)row * NQ);
        f32x4 v1 = *reinterpret_cast<const f32x4*>(s_part + (size_t)row * NQ + 4);
        float S = (v0[0] + v0[1]) + (v0[2] + v0[3]) + (v1[0] + v1[1]) + (v1[2] + v1[3]);
        acc += __logf(S - CDIAG) - ppos[row & (HALF_B - 1)];
    }
    #pragma unroll
    for (int off = 32; off >= 1; off >>= 1) acc += __shfl_xor(acc, off);
    __shared__ float ls[16];
    if ((tid & 63) == 0) ls[tid >> 6] = acc;
    __syncthreads();
    if (tid < 16) {
        float w = ls[tid];
        #pragma unroll
        for (int off = 8; off >= 1; off >>= 1) w += __shfl_xor(w, off);
        if (tid == 0) out[0] = w * (1.0f / (float)N_TOT);
    }
}

extern "C" void kernel_launch(void* const* d_in, const int* in_sizes, int n_in,
                              void* d_out, int out_size, void* d_ws, size_t ws_size,
                              hipStream_t stream) {
    const float* pi = (const float*)d_in[0];
    const float* pj = (const float*)d_in[1];
    float* out = (float*)d_out;

    char* ws = (char*)d_ws;
    unsigned short* z = (unsigned short*)ws;                         // 2 MiB
    float* ppos   = (float*)(ws + 2 * 1024 * 1024);                  // 16 KiB
    float* s_part = (float*)(ws + 2 * 1024 * 1024 + 16 * 1024);      // 256 KiB ([row][NQ])

    nrm_k<<<dim3(1024), dim3(256), 0, stream>>>(pi, pj, z, ppos);
    sim_k<<<dim3(N_TOT / BM, NQ), dim3(256), 0, stream>>>(z, s_part);
    red_k<<<dim3(1), dim3(1024), 0, stream>>>(s_part, ppos, out);
}

// Round 16
// 32.366 us; speedup vs baseline: 1.2123x; 1.0087x over previous
//
#include <hip/hip_runtime.h>
#include <hip/hip_bf16.h>

typedef __attribute__((ext_vector_type(8))) short short8;
typedef __attribute__((ext_vector_type(4))) float f32x4;

#define N_TOT 8192
#define HALF_B 4096
#define D 128
#define BM 128               // rows per block
#define BN 128               // cols per B-tile step
#define NQ 8                 // column slices (grid.y)
#define SLICE (N_TOT / NQ)   // 1024 cols per block
#define NSTEP (SLICE / BN)   // 8 steps
// z pre-scaled by SCALE, SCALE^2 = 2*log2(e): z@z^T = sim/T * log2(e)
#define SCALE 1.6986437f
#define CDIAG 7.3890561f     // e^2 == exp2(SCALE^2): diagonal term (R7-verified)

#if __has_builtin(__builtin_amdgcn_exp2f)
  #define EXP2(x) __builtin_amdgcn_exp2f(x)
#else
  #define EXP2(x) exp2f(x)
#endif

static __device__ inline unsigned short f2bf(float f) {
    unsigned int u = __builtin_bit_cast(unsigned int, f);
    u = (u + 0x7fffu + ((u >> 16) & 1u)) >> 16;
    return (unsigned short)u;
}

// async global->LDS, 16B per lane, LDS dest = wave-uniform base + lane*16
static __device__ __forceinline__ void gload16(const void* g, void* l) {
    __builtin_amdgcn_global_load_lds(
        (const __attribute__((address_space(1))) unsigned int*)g,
        (__attribute__((address_space(3))) unsigned int*)l, 16, 0, 0);
}

// Stage a 128x128 bf16 tile into 32 KB LDS, XOR-swizzled (row&15)<<4 via the
// GLOBAL source address (gload_lds writes LDS linearly - rule #21).
static __device__ __forceinline__ void stage_tile(const unsigned short* __restrict__ z,
                                                  int src_row, char* ldsbase, int tid) {
    int wv = tid >> 6, ln = tid & 63;
    const char* zb = (const char*)z;
    #pragma unroll
    for (int i = 0; i < 8; ++i) {
        int L  = wv * 8192 + i * 1024;        // wave-uniform LDS byte offset
        int Ll = L + ln * 16;                 // this lane's linear dest byte
        int r  = Ll >> 8;
        int c2 = (Ll & 255) ^ ((r & 15) << 4);
        gload16(zb + (size_t)(src_row + r) * 256 + c2, ldsbase + L);
    }
}

// swizzled LDS fragment read (16B), same involution as stage_tile
static __device__ __forceinline__ short8 ldsfrag(const char* ldsbase, int row, int kbyte) {
    int off = row * 256 + (kbyte ^ ((row & 15) << 4));
    return *reinterpret_cast<const short8*>(ldsbase + off);
}

// ---- Kernel 1: normalize row PAIRS, emit z + fp32 pos logits -------------
// grid 1024 x 256: wave w handles pair r = blk*4+w (rows r and r+4096)
__global__ __launch_bounds__(256) void nrm_k(const float* __restrict__ pi,
                                             const float* __restrict__ pj,
                                             unsigned short* __restrict__ z,
                                             float* __restrict__ ppos) {
    int tid = (int)threadIdx.x;
    int wid = tid >> 6, lane = tid & 63;
    int r = (int)blockIdx.x * 4 + wid;                         // pair index [0,4096)
    float2 va = *reinterpret_cast<const float2*>(pi + (size_t)r * D + lane * 2);
    float2 vb = *reinterpret_cast<const float2*>(pj + (size_t)r * D + lane * 2);
    float ssa = va.x * va.x + va.y * va.y;
    float ssb = vb.x * vb.x + vb.y * vb.y;
    float sab = va.x * vb.x + va.y * vb.y;
    #pragma unroll
    for (int off = 32; off >= 1; off >>= 1) {
        ssa += __shfl_xor(ssa, off);
        ssb += __shfl_xor(ssb, off);
        sab += __shfl_xor(sab, off);
    }
    float na = fmaxf(sqrtf(ssa), 1e-8f);
    float nb = fmaxf(sqrtf(ssb), 1e-8f);
    float inva = SCALE / na, invb = SCALE / nb;
    unsigned int pa = ((unsigned int)f2bf(va.y * inva) << 16) | (unsigned int)f2bf(va.x * inva);
    unsigned int pb = ((unsigned int)f2bf(vb.y * invb) << 16) | (unsigned int)f2bf(vb.x * invb);
    *reinterpret_cast<unsigned int*>(z + (size_t)r * D + lane * 2) = pa;
    *reinterpret_cast<unsigned int*>(z + (size_t)(r + HALF_B) * D + lane * 2) = pb;
    if (lane == 0) ppos[r] = 2.0f * sab / (na * nb);   // pos_sim / T, fp32
}

// ---- Kernel 2: LDS-staged z@z^T -> exp2 -> row partial sums --------------
__global__ __launch_bounds__(256, 2) void sim_k(const unsigned short* __restrict__ z,
                                                float* __restrict__ s_part) {
    __shared__ char lds[64 * 1024];
    char* Asm = lds;
    char* Bsm = lds + 32768;

    int tid  = (int)threadIdx.x;
    int lane = tid & 63;
    int wid  = tid >> 6;
    int lr   = lane & 15;     // A-row / B-col within 16-tile
    int kg   = lane >> 4;     // k-group
    int R0   = (int)blockIdx.x * BM;
    int C0   = (int)blockIdx.y * SLICE;

    stage_tile(z, R0, Asm, tid);
    stage_tile(z, C0, Bsm, tid);
    __syncthreads();

    // A fragments: wave's 32 rows x K=128, read once from LDS (32 VGPRs)
    short8 a[2][4];
    #pragma unroll
    for (int m = 0; m < 2; ++m)
        #pragma unroll
        for (int kt = 0; kt < 4; ++kt)
            a[m][kt] = ldsfrag(Asm, wid * 32 + m * 16 + lr, kg * 16 + kt * 64);

    float s[2][4];
    #pragma unroll
    for (int m = 0; m < 2; ++m)
        #pragma unroll
        for (int r = 0; r < 4; ++r) s[m][r] = 0.0f;

    for (int bs = 0; bs < NSTEP; ++bs) {
        if (bs) {
            __syncthreads();                       // readers done with Bsm
            stage_tile(z, C0 + bs * BN, Bsm, tid);
            __syncthreads();                       // stage visible
        }
        #pragma unroll
        for (int nt = 0; nt < 8; ++nt) {
            short8 b[4];
            #pragma unroll
            for (int kt = 0; kt < 4; ++kt)
                b[kt] = ldsfrag(Bsm, nt * 16 + lr, kg * 16 + kt * 64);
            #pragma unroll
            for (int m = 0; m < 2; ++m) {
                f32x4 acc = {0.0f, 0.0f, 0.0f, 0.0f};
                #pragma unroll
                for (int kt = 0; kt < 4; ++kt)
                    acc = __builtin_amdgcn_mfma_f32_16x16x32_bf16(a[m][kt], b[kt], acc, 0, 0, 0);
                #pragma unroll
                for (int r = 0; r < 4; ++r)
                    s[m][r] += EXP2(acc[r]);   // includes diag (== CDIAG, fixed in red_k)
            }
        }
    }

    // reduce across the 16 columns held by each 16-lane group
    #pragma unroll
    for (int off = 1; off <= 8; off <<= 1)
        #pragma unroll
        for (int m = 0; m < 2; ++m)
            #pragma unroll
            for (int r = 0; r < 4; ++r)
                s[m][r] += __shfl_xor(s[m][r], off);

    if (lr == 0) {
        int rowbase = R0 + wid * 32;
        #pragma unroll
        for (int m = 0; m < 2; ++m)
            #pragma unroll
            for (int r = 0; r < 4; ++r)
                s_part[(size_t)(rowbase + m * 16 + kg * 4 + r) * NQ + blockIdx.y] = s[m][r];
    }
}

// ---- Kernel 3: single-block finish: S -> log -> deterministic sum --------
// 1024 threads x 8 rows each; s_part[row][8] read as 2x float4 (coalesced).
__global__ __launch_bounds__(1024) void red_k(const float* __restrict__ s_part,
                                              const float* __restrict__ ppos,
                                              float* __restrict__ out) {
    int tid = (int)threadIdx.x;
    float acc = 0.0f;
    #pragma unroll
    for (int u = 0; u < 8; ++u) {
        int row = tid + u * 1024;
        f32x4 v0 = *reinterpret_cast<const f32x4*>(s_part + (size_t)row * NQ);
        f32x4 v1 = *reinterpret_cast<const f32x4*>(s_part + (size_t)row * NQ + 4);
        float S = (v0[0] + v0[1]) + (v0[2] + v0[3]) + (v1[0] + v1[1]) + (v1[2] + v1[3]);
        acc += __logf(S - CDIAG) - ppos[row & (HALF_B - 1)];
    }
    #pragma unroll
    for (int off = 32; off >= 1; off >>= 1) acc += __shfl_xor(acc, off);
    __shared__ float ls[16];
    if ((tid & 63) == 0) ls[tid >> 6] = acc;
    __syncthreads();
    if (tid < 16) {
        float w = ls[tid];
        #pragma unroll
        for (int off = 8; off >= 1; off >>= 1) w += __shfl_xor(w, off);
        if (tid == 0) out[0] = w * (1.0f / (float)N_TOT);
    }
}

extern "C" void kernel_launch(void* const* d_in, const int* in_sizes, int n_in,
                              void* d_out, int out_size, void* d_ws, size_t ws_size,
                              hipStream_t stream) {
    const float* pi = (const float*)d_in[0];
    const float* pj = (const float*)d_in[1];
    float* out = (float*)d_out;

    char* ws = (char*)d_ws;
    unsigned short* z = (unsigned short*)ws;                         // 2 MiB
    float* ppos   = (float*)(ws + 2 * 1024 * 1024);                  // 16 KiB
    float* s_part = (float*)(ws + 2 * 1024 * 1024 + 16 * 1024);      // 256 KiB ([row][NQ])

    nrm_k<<<dim3(1024), dim3(256), 0, stream>>>(pi, pj, z, ppos);
    sim_k<<<dim3(N_TOT / BM, NQ), dim3(256), 0, stream>>>(z, s_part);
    red_k<<<dim3(1), dim3(1024), 0, stream>>>(s_part, ppos, out);
}